// Round 1
// baseline (616.337 us; speedup 1.0000x reference)
//
#include <hip/hip_runtime.h>
#include <hip/hip_bf16.h>

// Problem constants
#define BB 2
#define CC 2048
#define MM 1024
#define HH 16
#define KK 64   // head dim for q/k and v

typedef __attribute__((ext_vector_type(8))) short bf16x8;
typedef __attribute__((ext_vector_type(4))) float f32x4;

__device__ __forceinline__ short f2bf(float f) {
    union { float f; unsigned int i; } u; u.f = f;
    unsigned int r = u.i + 0x7fffu + ((u.i >> 16) & 1u);
    return (short)(r >> 16);
}

__device__ __forceinline__ f32x4 mfma16(bf16x8 a, bf16x8 b, f32x4 c) {
    return __builtin_amdgcn_mfma_f32_16x16x32_bf16(a, b, c, 0, 0, 0);
}

// ---------------------------------------------------------------------------
// prep: fp32 -> bf16 conversions + weight transposes.
//   xq[b][c][m], xkv[b][c][m]                  (row-major, m contiguous)
//   wqt/wkt/wvt[h][kout][m]   = w[h][m][kout]  (m contiguous)
//   wot[m][h*64+v]            = wo[h][v][m]    (hv contiguous)
// grid: 4096 x 256 = 1,048,576 threads exactly (each: 4 input elems + 1 weight elem)
// ---------------------------------------------------------------------------
__global__ __launch_bounds__(256) void prep_kernel(
    const float* __restrict__ qin, const float* __restrict__ kvin,
    const float* __restrict__ wq, const float* __restrict__ wk,
    const float* __restrict__ wv, const float* __restrict__ wo,
    short* __restrict__ xq, short* __restrict__ xkv,
    short* __restrict__ wqt, short* __restrict__ wkt,
    short* __restrict__ wvt, short* __restrict__ wot)
{
    int tid = blockIdx.x * 256 + threadIdx.x;   // [0, 1M)
    int i4 = tid * 4;
    {
        float4 a = *(const float4*)(qin + i4);
        float4 b = *(const float4*)(kvin + i4);
        short4 sa, sb;
        sa.x = f2bf(a.x); sa.y = f2bf(a.y); sa.z = f2bf(a.z); sa.w = f2bf(a.w);
        sb.x = f2bf(b.x); sb.y = f2bf(b.y); sb.z = f2bf(b.z); sb.w = f2bf(b.w);
        *(short4*)(xq + i4) = sa;
        *(short4*)(xkv + i4) = sb;
    }
    {
        // tid = h*65536 + k*1024 + m  (dst layout [h][k][m])
        int m = tid & (MM - 1);
        int k = (tid >> 10) & (KK - 1);
        int h = tid >> 16;
        int src = (h * MM + m) * KK + k;
        wqt[tid] = f2bf(wq[src]);
        wkt[tid] = f2bf(wk[src]);
        wvt[tid] = f2bf(wv[src]);
        // wot: tid = m2*1024 + hv ; wo flat = hv*1024 + m2
        int hv = tid & 1023;
        int m2 = tid >> 10;
        wot[tid] = f2bf(wo[hv * MM + m2]);
    }
}

// ---------------------------------------------------------------------------
// proj: per (b,h, ctile) computes Q,K,V 64x64 tiles. 4 waves x 16 rows.
// Register-only (operands L2/L3-resident).
//   Qv/Kv [bh][c][k]  (k contiguous)
//   Vt    [bh][v][c]  (c contiguous)  -- transposed for PV B-fragments
// grid: (32 ctiles, 32 bh)
// ---------------------------------------------------------------------------
__global__ __launch_bounds__(256) void proj_kernel(
    const short* __restrict__ xq, const short* __restrict__ xkv,
    const short* __restrict__ wqt, const short* __restrict__ wkt,
    const short* __restrict__ wvt,
    short* __restrict__ Qv, short* __restrict__ Kv, short* __restrict__ Vt)
{
    int ctile = blockIdx.x;
    int bh = blockIdx.y;
    int b = bh >> 4, h = bh & 15;
    int wave = threadIdx.x >> 6;
    int lane = threadIdx.x & 63;
    int g = lane >> 4, li = lane & 15;
    int row0 = ctile * 64 + wave * 16;

    const short* xqA = xq + ((size_t)(b * CC + row0 + li)) * MM + g * 8;
    const short* xkA = xkv + ((size_t)(b * CC + row0 + li)) * MM + g * 8;
    const short* wqB = wqt + ((size_t)(h * KK + li)) * MM + g * 8;
    const short* wkB = wkt + ((size_t)(h * KK + li)) * MM + g * 8;
    const short* wvB = wvt + ((size_t)(h * KK + li)) * MM + g * 8;

    f32x4 aq[4], ak[4], av[4];
    #pragma unroll
    for (int i = 0; i < 4; ++i) {
        aq[i] = (f32x4){0.f, 0.f, 0.f, 0.f};
        ak[i] = (f32x4){0.f, 0.f, 0.f, 0.f};
        av[i] = (f32x4){0.f, 0.f, 0.f, 0.f};
    }

    for (int mt = 0; mt < MM; mt += 64) {
        bf16x8 a_q0 = *(const bf16x8*)(xqA + mt);
        bf16x8 a_q1 = *(const bf16x8*)(xqA + mt + 32);
        bf16x8 a_k0 = *(const bf16x8*)(xkA + mt);
        bf16x8 a_k1 = *(const bf16x8*)(xkA + mt + 32);
        #pragma unroll
        for (int cb = 0; cb < 4; ++cb) {
            int woff = cb * 16 * MM + mt;
            bf16x8 bq0 = *(const bf16x8*)(wqB + woff);
            bf16x8 bq1 = *(const bf16x8*)(wqB + woff + 32);
            bf16x8 bk0 = *(const bf16x8*)(wkB + woff);
            bf16x8 bk1 = *(const bf16x8*)(wkB + woff + 32);
            bf16x8 bv0 = *(const bf16x8*)(wvB + woff);
            bf16x8 bv1 = *(const bf16x8*)(wvB + woff + 32);
            aq[cb] = mfma16(a_q0, bq0, aq[cb]);
            aq[cb] = mfma16(a_q1, bq1, aq[cb]);
            ak[cb] = mfma16(a_k0, bk0, ak[cb]);
            ak[cb] = mfma16(a_k1, bk1, ak[cb]);
            av[cb] = mfma16(a_k0, bv0, av[cb]);
            av[cb] = mfma16(a_k1, bv1, av[cb]);
        }
    }

    #pragma unroll
    for (int cb = 0; cb < 4; ++cb) {
        #pragma unroll
        for (int r = 0; r < 4; ++r) {
            int c = row0 + g * 4 + r;          // D row = (lane>>4)*4 + reg
            int kout = cb * 16 + li;           // D col = lane&15
            Qv[((size_t)bh * CC + c) * KK + kout] = f2bf(aq[cb][r]);
            Kv[((size_t)bh * CC + c) * KK + kout] = f2bf(ak[cb][r]);
            Vt[((size_t)bh * KK + kout) * CC + c] = f2bf(av[cb][r]);
        }
    }
}

// ---------------------------------------------------------------------------
// attn: flash-style online-softmax attention per (b,h).
// Block = 4 waves, each wave owns 16 query rows (DBLK=64), key tiles of 64.
// S tile [16 d][64 c]: D-frag col = c (lane&15), row = d ((lane>>4)*4+reg)
//   -> softmax over c = 4 per-lane values + 16-lane shfl_xor butterfly.
// P transposed through per-wave padded LDS [16][72] into PV A-fragments.
// pre[b][d][h*64+v] bf16.
// grid: (32 dtiles, 32 bh)
// ---------------------------------------------------------------------------
__global__ __launch_bounds__(256) void attn_kernel(
    const short* __restrict__ Qv, const short* __restrict__ Kv,
    const short* __restrict__ Vt, short* __restrict__ pre)
{
    int dtile = blockIdx.x;
    int bh = blockIdx.y;
    int b = bh >> 4, h = bh & 15;
    int wave = threadIdx.x >> 6, lane = threadIdx.x & 63;
    int g = lane >> 4, li = lane & 15;
    int d0 = dtile * 64 + wave * 16;

    __shared__ short plds[4][16][72];   // 72*2 = 144 B row stride (16B multiple)

    const short* qb = Qv + ((size_t)bh * CC + d0 + li) * KK + g * 8;
    bf16x8 qf0 = *(const bf16x8*)qb;
    bf16x8 qf1 = *(const bf16x8*)(qb + 32);

    f32x4 o[4];
    #pragma unroll
    for (int i = 0; i < 4; ++i) o[i] = (f32x4){0.f, 0.f, 0.f, 0.f};
    float mrun[4] = {-INFINITY, -INFINITY, -INFINITY, -INFINITY};
    float lrun[4] = {0.f, 0.f, 0.f, 0.f};
    const float sc = 0.125f;   // 1/sqrt(64)

    const short* kbase = Kv + (size_t)bh * CC * KK;
    const short* vbase = Vt + (size_t)bh * KK * CC;

    for (int ct = 0; ct < CC; ct += 64) {
        // ---- S = Q K^T (scaled later), 16x64 per wave ----
        f32x4 s[4];
        #pragma unroll
        for (int cb = 0; cb < 4; ++cb) {
            const short* kb = kbase + (size_t)(ct + cb * 16 + li) * KK + g * 8;
            bf16x8 k0 = *(const bf16x8*)kb;
            bf16x8 k1 = *(const bf16x8*)(kb + 32);
            f32x4 z = (f32x4){0.f, 0.f, 0.f, 0.f};
            z = mfma16(qf0, k0, z);
            z = mfma16(qf1, k1, z);
            s[cb] = z;
        }
        // ---- online softmax over c ----
        float alpha[4];
        #pragma unroll
        for (int r = 0; r < 4; ++r) {
            float s0 = s[0][r] * sc, s1 = s[1][r] * sc;
            float s2 = s[2][r] * sc, s3 = s[3][r] * sc;
            float tm = fmaxf(fmaxf(s0, s1), fmaxf(s2, s3));
            tm = fmaxf(tm, __shfl_xor(tm, 1));
            tm = fmaxf(tm, __shfl_xor(tm, 2));
            tm = fmaxf(tm, __shfl_xor(tm, 4));
            tm = fmaxf(tm, __shfl_xor(tm, 8));
            float mnew = fmaxf(mrun[r], tm);
            float al = expf(mrun[r] - mnew);
            float p0 = expf(s0 - mnew), p1 = expf(s1 - mnew);
            float p2 = expf(s2 - mnew), p3 = expf(s3 - mnew);
            float tl = (p0 + p1) + (p2 + p3);
            tl += __shfl_xor(tl, 1);
            tl += __shfl_xor(tl, 2);
            tl += __shfl_xor(tl, 4);
            tl += __shfl_xor(tl, 8);
            lrun[r] = lrun[r] * al + tl;
            mrun[r] = mnew;
            alpha[r] = al;
            // write P row d = g*4+r to LDS (transpose staging)
            plds[wave][g * 4 + r][0  + li] = f2bf(p0);
            plds[wave][g * 4 + r][16 + li] = f2bf(p1);
            plds[wave][g * 4 + r][32 + li] = f2bf(p2);
            plds[wave][g * 4 + r][48 + li] = f2bf(p3);
        }
        // ---- rescale O ----
        #pragma unroll
        for (int cbv = 0; cbv < 4; ++cbv) {
            #pragma unroll
            for (int r = 0; r < 4; ++r) o[cbv][r] *= alpha[r];
        }
        // ---- read P as A-fragments (row = li = d, k = c_local) ----
        bf16x8 pf0 = *(const bf16x8*)&plds[wave][li][g * 8];
        bf16x8 pf1 = *(const bf16x8*)&plds[wave][li][32 + g * 8];
        // ---- O += P V ----
        #pragma unroll
        for (int cbv = 0; cbv < 4; ++cbv) {
            const short* vb = vbase + (size_t)(cbv * 16 + li) * CC + ct + g * 8;
            bf16x8 v0 = *(const bf16x8*)vb;
            bf16x8 v1 = *(const bf16x8*)(vb + 32);
            o[cbv] = mfma16(pf0, v0, o[cbv]);
            o[cbv] = mfma16(pf1, v1, o[cbv]);
        }
    }

    // ---- epilogue: normalize and store pre[b][d][h*64+v] ----
    #pragma unroll
    for (int cbv = 0; cbv < 4; ++cbv) {
        #pragma unroll
        for (int r = 0; r < 4; ++r) {
            int d = d0 + g * 4 + r;
            float val = o[cbv][r] / lrun[r];
            pre[((size_t)b * CC + d) * (HH * KK) + h * KK + cbv * 16 + li] = f2bf(val);
        }
    }
}

// ---------------------------------------------------------------------------
// outproj: out[bd][m] = sum_hv pre[bd][hv] * wot[m][hv], fp32 output.
// grid: (16 mtiles, 64 row tiles)
// ---------------------------------------------------------------------------
__global__ __launch_bounds__(256) void outproj_kernel(
    const short* __restrict__ pre, const short* __restrict__ wot,
    float* __restrict__ out)
{
    int mtile = blockIdx.x;
    int rtile = blockIdx.y;
    int wave = threadIdx.x >> 6, lane = threadIdx.x & 63;
    int g = lane >> 4, li = lane & 15;
    int row0 = rtile * 64 + wave * 16;

    const short* aA = pre + (size_t)(row0 + li) * (HH * KK) + g * 8;
    f32x4 acc[4];
    #pragma unroll
    for (int i = 0; i < 4; ++i) acc[i] = (f32x4){0.f, 0.f, 0.f, 0.f};

    for (int kt = 0; kt < HH * KK; kt += 64) {
        bf16x8 a0 = *(const bf16x8*)(aA + kt);
        bf16x8 a1 = *(const bf16x8*)(aA + kt + 32);
        #pragma unroll
        for (int cb = 0; cb < 4; ++cb) {
            const short* bB = wot + (size_t)(mtile * 64 + cb * 16 + li) * (HH * KK) + kt + g * 8;
            bf16x8 b0 = *(const bf16x8*)bB;
            bf16x8 b1 = *(const bf16x8*)(bB + 32);
            acc[cb] = mfma16(a0, b0, acc[cb]);
            acc[cb] = mfma16(a1, b1, acc[cb]);
        }
    }

    #pragma unroll
    for (int cb = 0; cb < 4; ++cb) {
        #pragma unroll
        for (int r = 0; r < 4; ++r) {
            out[(size_t)(row0 + g * 4 + r) * MM + mtile * 64 + cb * 16 + li] = acc[cb][r];
        }
    }
}

// ---------------------------------------------------------------------------
extern "C" void kernel_launch(void* const* d_in, const int* in_sizes, int n_in,
                              void* d_out, int out_size, void* d_ws, size_t ws_size,
                              hipStream_t stream)
{
    const float* kvin = (const float*)d_in[0];
    const float* qin  = (const float*)d_in[1];
    const float* wq   = (const float*)d_in[2];
    const float* wk   = (const float*)d_in[3];
    const float* wv   = (const float*)d_in[4];
    const float* wo   = (const float*)d_in[5];
    float* out = (float*)d_out;

    char* ws = (char*)d_ws;
    const size_t SZ_X = (size_t)BB * CC * MM * 2;   // 8 MB  (bf16 [b][c][m]-sized)
    const size_t SZ_W = (size_t)HH * MM * KK * 2;   // 2 MB
    short* xq  = (short*)(ws);
    short* xkv = (short*)(ws + SZ_X);
    short* wqt = (short*)(ws + 2 * SZ_X);
    short* wkt = (short*)(ws + 2 * SZ_X + SZ_W);
    short* wvt = (short*)(ws + 2 * SZ_X + 2 * SZ_W);
    short* wot = (short*)(ws + 2 * SZ_X + 3 * SZ_W);
    short* Qv  = (short*)(ws + 2 * SZ_X + 4 * SZ_W);
    short* Kv  = (short*)(ws + 3 * SZ_X + 4 * SZ_W);
    short* Vt  = (short*)(ws + 4 * SZ_X + 4 * SZ_W);
    short* pre = (short*)(ws + 5 * SZ_X + 4 * SZ_W);
    // total workspace use: 56 MB

    prep_kernel<<<4096, 256, 0, stream>>>(qin, kvin, wq, wk, wv, wo,
                                          xq, xkv, wqt, wkt, wvt, wot);
    proj_kernel<<<dim3(32, 32), 256, 0, stream>>>(xq, xkv, wqt, wkt, wvt, Qv, Kv, Vt);
    attn_kernel<<<dim3(32, 32), 256, 0, stream>>>(Qv, Kv, Vt, pre);
    outproj_kernel<<<dim3(16, 64), 256, 0, stream>>>(pre, wot, out);
}

// Round 2
// 445.212 us; speedup vs baseline: 1.3844x; 1.3844x over previous
//
#include <hip/hip_runtime.h>
#include <hip/hip_bf16.h>

#define BB 2
#define CC 2048
#define MM 1024
#define HH 16
#define KK 64

typedef __attribute__((ext_vector_type(8))) short bf16x8;
typedef __attribute__((ext_vector_type(4))) float f32x4;

__device__ __forceinline__ short f2bf(float f) {
    union { float f; unsigned int i; } u; u.f = f;
    unsigned int r = u.i + 0x7fffu + ((u.i >> 16) & 1u);
    return (short)(r >> 16);
}

__device__ __forceinline__ unsigned int cvtpk(float lo, float hi) {
    unsigned int d;
    asm("v_cvt_pk_bf16_f32 %0, %1, %2" : "=v"(d) : "v"(lo), "v"(hi));
    return d;
}

__device__ __forceinline__ float exp2v(float x) {
    float r;
    asm("v_exp_f32 %0, %1" : "=v"(r) : "v"(x));
    return r;
}

__device__ __forceinline__ f32x4 mfma16(bf16x8 a, bf16x8 b, f32x4 c) {
    return __builtin_amdgcn_mfma_f32_16x16x32_bf16(a, b, c, 0, 0, 0);
}

// ---------------------------------------------------------------------------
// prep: coalesced conversions + tile transposes (64x64 LDS tiles).
//   blocks 0..255   : wq/wk/wv  [h][m][k] -> [h][k][m] bf16
//   blocks 256..511 : wo        [hv][m]   -> [m][hv]   bf16
//   blocks 512..1023: qin/kvin  fp32 -> bf16 (straight copy)
// ---------------------------------------------------------------------------
__global__ __launch_bounds__(256) void prep_kernel(
    const float* __restrict__ qin, const float* __restrict__ kvin,
    const float* __restrict__ wq, const float* __restrict__ wk,
    const float* __restrict__ wv, const float* __restrict__ wo,
    short* __restrict__ xq, short* __restrict__ xkv,
    short* __restrict__ wqt, short* __restrict__ wkt,
    short* __restrict__ wvt, short* __restrict__ wot)
{
    __shared__ short tl[64][72];   // 144 B row stride (16B aligned)
    int b = blockIdx.x;
    int tid = threadIdx.x;

    if (b < 512) {
        int row = tid >> 2;           // 0..63
        int c0 = (tid & 3) * 16;      // 0/16/32/48
        int nw = (b < 256) ? 3 : 1;
        for (int w = 0; w < nw; ++w) {
            const float* src; short* dst; int srcStride, dstStride;
            if (b < 256) {
                int h = b >> 4, m0 = (b & 15) * 64;
                const float* wsrc = (w == 0) ? wq : (w == 1) ? wk : wv;
                short* wdst = (w == 0) ? wqt : (w == 1) ? wkt : wvt;
                src = wsrc + ((size_t)h * MM + m0) * KK;   // rows = m, cols = k
                srcStride = KK;
                dst = wdst + (size_t)h * KK * MM + m0;     // rows = k, stride MM
                dstStride = MM;
            } else {
                int b2 = b - 256;
                int hv0 = (b2 >> 4) * 64, m0 = (b2 & 15) * 64;
                src = wo + (size_t)hv0 * MM + m0;          // rows = hv, cols = m
                srcStride = MM;
                dst = wot + (size_t)m0 * (HH * KK) + hv0;  // rows = m, stride 1024
                dstStride = HH * KK;
            }
            float4 f0 = *(const float4*)(src + row * srcStride + c0);
            float4 f1 = *(const float4*)(src + row * srcStride + c0 + 4);
            float4 f2 = *(const float4*)(src + row * srcStride + c0 + 8);
            float4 f3 = *(const float4*)(src + row * srcStride + c0 + 12);
            tl[c0 + 0][row] = f2bf(f0.x);  tl[c0 + 1][row] = f2bf(f0.y);
            tl[c0 + 2][row] = f2bf(f0.z);  tl[c0 + 3][row] = f2bf(f0.w);
            tl[c0 + 4][row] = f2bf(f1.x);  tl[c0 + 5][row] = f2bf(f1.y);
            tl[c0 + 6][row] = f2bf(f1.z);  tl[c0 + 7][row] = f2bf(f1.w);
            tl[c0 + 8][row] = f2bf(f2.x);  tl[c0 + 9][row] = f2bf(f2.y);
            tl[c0 + 10][row] = f2bf(f2.z); tl[c0 + 11][row] = f2bf(f2.w);
            tl[c0 + 12][row] = f2bf(f3.x); tl[c0 + 13][row] = f2bf(f3.y);
            tl[c0 + 14][row] = f2bf(f3.z); tl[c0 + 15][row] = f2bf(f3.w);
            __syncthreads();
            int k = tid >> 2, s0 = (tid & 3) * 16;
            bf16x8 o0 = *(bf16x8*)&tl[k][s0];
            bf16x8 o1 = *(bf16x8*)&tl[k][s0 + 8];
            *(bf16x8*)(dst + (size_t)k * dstStride + s0) = o0;
            *(bf16x8*)(dst + (size_t)k * dstStride + s0 + 8) = o1;
            __syncthreads();
        }
    } else {
        // x conversion: 512 blocks x 256 threads x 8 float4 per array
        int t = (b - 512) * 256 + tid;
        const float4* q4 = (const float4*)qin;
        const float4* k4 = (const float4*)kvin;
        #pragma unroll
        for (int i = 0; i < 8; ++i) {
            int idx = t + i * 131072;
            float4 a = q4[idx], c = k4[idx];
            short4 sa, sc;
            sa.x = f2bf(a.x); sa.y = f2bf(a.y); sa.z = f2bf(a.z); sa.w = f2bf(a.w);
            sc.x = f2bf(c.x); sc.y = f2bf(c.y); sc.z = f2bf(c.z); sc.w = f2bf(c.w);
            *(short4*)(xq + (size_t)idx * 4) = sa;
            *(short4*)(xkv + (size_t)idx * 4) = sc;
        }
    }
}

// ---------------------------------------------------------------------------
// proj: per (b,h,ctile): Q,K,V 64x64 tiles. Wave w owns kout block w*16..w*16+15
// for ALL 64 c rows (4 rowgroups) -> no weight-read duplication across waves.
// Q is pre-scaled by 0.125*log2(e) (folded softmax scale for exp2 in attn).
//   Qv/Kv [bh][c][k]  (k contiguous),  Vt [bh][v][c] (c contiguous)
// ---------------------------------------------------------------------------
__global__ __launch_bounds__(256) void proj_kernel(
    const short* __restrict__ xq, const short* __restrict__ xkv,
    const short* __restrict__ wqt, const short* __restrict__ wkt,
    const short* __restrict__ wvt,
    short* __restrict__ Qv, short* __restrict__ Kv, short* __restrict__ Vt)
{
    int ctile = blockIdx.x;
    int bh = blockIdx.y;
    int b = bh >> 4, h = bh & 15;
    int w = threadIdx.x >> 6;
    int lane = threadIdx.x & 63;
    int g = lane >> 4, li = lane & 15;

    const short* xa = xq  + (((size_t)b * CC + ctile * 64 + li) << 10) + g * 8;
    const short* ka = xkv + (((size_t)b * CC + ctile * 64 + li) << 10) + g * 8;
    int wrow = h * KK + w * 16 + li;
    const short* wqB = wqt + ((size_t)wrow << 10) + g * 8;
    const short* wkB = wkt + ((size_t)wrow << 10) + g * 8;
    const short* wvB = wvt + ((size_t)wrow << 10) + g * 8;

    f32x4 aq[4], ak[4], av[4];
    #pragma unroll
    for (int i = 0; i < 4; ++i) {
        aq[i] = (f32x4){0.f, 0.f, 0.f, 0.f};
        ak[i] = (f32x4){0.f, 0.f, 0.f, 0.f};
        av[i] = (f32x4){0.f, 0.f, 0.f, 0.f};
    }

    for (int mt = 0; mt < MM; mt += 64) {
        bf16x8 bq0 = *(const bf16x8*)(wqB + mt);
        bf16x8 bq1 = *(const bf16x8*)(wqB + mt + 32);
        bf16x8 bk0 = *(const bf16x8*)(wkB + mt);
        bf16x8 bk1 = *(const bf16x8*)(wkB + mt + 32);
        bf16x8 bv0 = *(const bf16x8*)(wvB + mt);
        bf16x8 bv1 = *(const bf16x8*)(wvB + mt + 32);
        #pragma unroll
        for (int rg = 0; rg < 4; ++rg) {
            size_t ro = (size_t)rg * 16 * MM + mt;
            bf16x8 aq0 = *(const bf16x8*)(xa + ro);
            bf16x8 aq1 = *(const bf16x8*)(xa + ro + 32);
            bf16x8 ak0 = *(const bf16x8*)(ka + ro);
            bf16x8 ak1 = *(const bf16x8*)(ka + ro + 32);
            aq[rg] = mfma16(aq0, bq0, aq[rg]);
            aq[rg] = mfma16(aq1, bq1, aq[rg]);
            ak[rg] = mfma16(ak0, bk0, ak[rg]);
            ak[rg] = mfma16(ak1, bk1, ak[rg]);
            av[rg] = mfma16(ak0, bv0, av[rg]);
            av[rg] = mfma16(ak1, bv1, av[rg]);
        }
    }

    const float SCQ = 0.125f * 1.44269504f;   // softmax scale * log2(e)
    int kout = w * 16 + li;
    #pragma unroll
    for (int rg = 0; rg < 4; ++rg) {
        int c = ctile * 64 + rg * 16 + g * 4;
        #pragma unroll
        for (int r = 0; r < 4; ++r) {
            Qv[((size_t)bh * CC + c + r) * KK + kout] = f2bf(aq[rg][r] * SCQ);
            Kv[((size_t)bh * CC + c + r) * KK + kout] = f2bf(ak[rg][r]);
        }
        uint2 pv;
        pv.x = cvtpk(av[rg][0], av[rg][1]);
        pv.y = cvtpk(av[rg][2], av[rg][3]);
        *(uint2*)(Vt + ((size_t)bh * KK + kout) * CC + c) = pv;
    }
}

// ---------------------------------------------------------------------------
// attn: non-online softmax (scores ~N(0,1), no overflow risk), swapped QK^T.
// Wave owns 32 queries (two 16-col halves A/B), block = 4 waves = 128 queries.
// S^T = mfma(K,Q): lane holds P[c = ct+cb*16+g*4+r][d = d0+li] -> softmax is
// per-lane exp2 + partial sum (reduced once at the end, zero in-loop shuffles).
// P^T -> LDS (XOR-swizzled dword layout, b64 writes / b128 reads, conflict-min)
// PV: O^T = mfma(V^T, P^T).  pre[b][d][h*64+v] bf16.
// grid: (16 dtiles, 32 bh)
// ---------------------------------------------------------------------------
__global__ __launch_bounds__(256) void attn_kernel(
    const short* __restrict__ Qv, const short* __restrict__ Kv,
    const short* __restrict__ Vt, short* __restrict__ pre)
{
    int dtile = blockIdx.x;
    int bh = blockIdx.y;
    int b = bh >> 4, h = bh & 15;
    int wave = threadIdx.x >> 6, lane = threadIdx.x & 63;
    int g = lane >> 4, li = lane & 15;
    int d0 = dtile * 128 + wave * 32;

    __shared__ unsigned int plds[4 * 1024];   // 16 KB, 1024 dwords per wave

    // XOR swizzle (dword address space, bits 2..4) - keeps b64/b128 alignment
    int sw = ((li & 3) << 3) | (((li >> 2) & 1) << 2);
    unsigned int* wbase = plds + wave * 1024 + li * 32;
    unsigned int* wa0 = wbase + (((0 << 3) | (g << 1)) ^ sw);
    unsigned int* wa1 = wbase + (((1 << 3) | (g << 1)) ^ sw);
    unsigned int* wa2 = wbase + (((2 << 3) | (g << 1)) ^ sw);
    unsigned int* wa3 = wbase + (((3 << 3) | (g << 1)) ^ sw);
    unsigned int* ra0 = wbase + (((0 << 4) | (g << 2)) ^ sw);
    unsigned int* ra1 = wbase + (((1 << 4) | (g << 2)) ^ sw);

    // Q fragments (B operand): halves A (d0+li) and B (d0+16+li); Q pre-scaled
    const short* qb = Qv + ((size_t)bh * CC + d0 + li) * KK + g * 8;
    bf16x8 qA0 = *(const bf16x8*)qb;
    bf16x8 qA1 = *(const bf16x8*)(qb + 32);
    bf16x8 qB0 = *(const bf16x8*)(qb + 16 * KK);
    bf16x8 qB1 = *(const bf16x8*)(qb + 16 * KK + 32);

    f32x4 oA[4], oB[4];
    #pragma unroll
    for (int i = 0; i < 4; ++i) {
        oA[i] = (f32x4){0.f, 0.f, 0.f, 0.f};
        oB[i] = (f32x4){0.f, 0.f, 0.f, 0.f};
    }
    float lsA = 0.f, lsB = 0.f;

    const short* kT = Kv + (size_t)bh * CC * KK + li * KK + g * 8;
    const short* vT = Vt + (size_t)bh * KK * CC + li * CC + g * 8;

    for (int ct = 0; ct < CC; ct += 64) {
        // ---- S^T for both halves ----
        f32x4 sA[4], sB[4];
        #pragma unroll
        for (int cb = 0; cb < 4; ++cb) {
            const short* kp = kT + (size_t)cb * 16 * KK;
            bf16x8 k0 = *(const bf16x8*)kp;
            bf16x8 k1 = *(const bf16x8*)(kp + 32);
            f32x4 z = (f32x4){0.f, 0.f, 0.f, 0.f};
            z = mfma16(k0, qA0, z);
            sA[cb] = mfma16(k1, qA1, z);
            f32x4 z2 = (f32x4){0.f, 0.f, 0.f, 0.f};
            z2 = mfma16(k0, qB0, z2);
            sB[cb] = mfma16(k1, qB1, z2);
        }
        kT += 64 * KK;
        // ---- exp2 + partial sums + pack + LDS (half A then half B) ----
        {
            float p[16];
            #pragma unroll
            for (int cb = 0; cb < 4; ++cb)
                #pragma unroll
                for (int r = 0; r < 4; ++r) p[cb * 4 + r] = exp2v(sA[cb][r]);
            float t0 = (p[0] + p[1]) + (p[2] + p[3]);
            float t1 = (p[4] + p[5]) + (p[6] + p[7]);
            float t2 = (p[8] + p[9]) + (p[10] + p[11]);
            float t3 = (p[12] + p[13]) + (p[14] + p[15]);
            lsA += (t0 + t1) + (t2 + t3);
            uint2 v;
            v.x = cvtpk(p[0], p[1]);  v.y = cvtpk(p[2], p[3]);   *(uint2*)wa0 = v;
            v.x = cvtpk(p[4], p[5]);  v.y = cvtpk(p[6], p[7]);   *(uint2*)wa1 = v;
            v.x = cvtpk(p[8], p[9]);  v.y = cvtpk(p[10], p[11]); *(uint2*)wa2 = v;
            v.x = cvtpk(p[12], p[13]); v.y = cvtpk(p[14], p[15]); *(uint2*)wa3 = v;
        }
        {
            float p[16];
            #pragma unroll
            for (int cb = 0; cb < 4; ++cb)
                #pragma unroll
                for (int r = 0; r < 4; ++r) p[cb * 4 + r] = exp2v(sB[cb][r]);
            float t0 = (p[0] + p[1]) + (p[2] + p[3]);
            float t1 = (p[4] + p[5]) + (p[6] + p[7]);
            float t2 = (p[8] + p[9]) + (p[10] + p[11]);
            float t3 = (p[12] + p[13]) + (p[14] + p[15]);
            lsB += (t0 + t1) + (t2 + t3);
            uint2 v;
            v.x = cvtpk(p[0], p[1]);  v.y = cvtpk(p[2], p[3]);   *(uint2*)(wa0 + 512) = v;
            v.x = cvtpk(p[4], p[5]);  v.y = cvtpk(p[6], p[7]);   *(uint2*)(wa1 + 512) = v;
            v.x = cvtpk(p[8], p[9]);  v.y = cvtpk(p[10], p[11]); *(uint2*)(wa2 + 512) = v;
            v.x = cvtpk(p[12], p[13]); v.y = cvtpk(p[14], p[15]); *(uint2*)(wa3 + 512) = v;
        }
        // ---- read P^T fragments (B operand) ----
        bf16x8 pA0 = *(bf16x8*)ra0;
        bf16x8 pA1 = *(bf16x8*)ra1;
        bf16x8 pB0 = *(bf16x8*)(ra0 + 512);
        bf16x8 pB1 = *(bf16x8*)(ra1 + 512);
        // ---- O^T += V^T P^T ----
        #pragma unroll
        for (int cbv = 0; cbv < 4; ++cbv) {
            const short* vp = vT + (size_t)cbv * 16 * CC + ct;
            bf16x8 v0 = *(const bf16x8*)vp;
            bf16x8 v1 = *(const bf16x8*)(vp + 32);
            oA[cbv] = mfma16(v0, pA0, oA[cbv]);
            oA[cbv] = mfma16(v1, pA1, oA[cbv]);
            oB[cbv] = mfma16(v0, pB0, oB[cbv]);
            oB[cbv] = mfma16(v1, pB1, oB[cbv]);
        }
    }

    // ---- final sum reduce (over the 4 g-groups) + normalize + store ----
    lsA += __shfl_xor(lsA, 16); lsA += __shfl_xor(lsA, 32);
    lsB += __shfl_xor(lsB, 16); lsB += __shfl_xor(lsB, 32);
    float rA = 1.0f / lsA, rB = 1.0f / lsB;

    short* prA = pre + ((size_t)b * CC + d0 + li) * (HH * KK) + h * KK + g * 4;
    short* prB = prA + (size_t)16 * (HH * KK);
    #pragma unroll
    for (int cbv = 0; cbv < 4; ++cbv) {
        uint2 u;
        u.x = cvtpk(oA[cbv][0] * rA, oA[cbv][1] * rA);
        u.y = cvtpk(oA[cbv][2] * rA, oA[cbv][3] * rA);
        *(uint2*)(prA + cbv * 16) = u;
        u.x = cvtpk(oB[cbv][0] * rB, oB[cbv][1] * rB);
        u.y = cvtpk(oB[cbv][2] * rB, oB[cbv][3] * rB);
        *(uint2*)(prB + cbv * 16) = u;
    }
}

// ---------------------------------------------------------------------------
// outproj: out[bd][m] = sum_hv pre[bd][hv] * wot[m][hv], fp32 out.
// Wave w owns m block w*16.. for all 64 rows (no wot duplication).
// grid: (16 mtiles, 64 row tiles)
// ---------------------------------------------------------------------------
__global__ __launch_bounds__(256) void outproj_kernel(
    const short* __restrict__ pre, const short* __restrict__ wot,
    float* __restrict__ out)
{
    int mtile = blockIdx.x;
    int rtile = blockIdx.y;
    int w = threadIdx.x >> 6, lane = threadIdx.x & 63;
    int g = lane >> 4, li = lane & 15;

    const short* aA = pre + ((size_t)rtile * 64 + li) * (HH * KK) + g * 8;
    const short* bB = wot + ((size_t)(mtile * 64 + w * 16 + li)) * (HH * KK) + g * 8;

    f32x4 acc[4];
    #pragma unroll
    for (int i = 0; i < 4; ++i) acc[i] = (f32x4){0.f, 0.f, 0.f, 0.f};

    for (int kt = 0; kt < HH * KK; kt += 64) {
        bf16x8 b0 = *(const bf16x8*)(bB + kt);
        bf16x8 b1 = *(const bf16x8*)(bB + kt + 32);
        #pragma unroll
        for (int rg = 0; rg < 4; ++rg) {
            size_t ro = (size_t)rg * 16 * (HH * KK) + kt;
            bf16x8 a0 = *(const bf16x8*)(aA + ro);
            bf16x8 a1 = *(const bf16x8*)(aA + ro + 32);
            acc[rg] = mfma16(a0, b0, acc[rg]);
            acc[rg] = mfma16(a1, b1, acc[rg]);
        }
    }

    #pragma unroll
    for (int rg = 0; rg < 4; ++rg) {
        int row = rtile * 64 + rg * 16 + g * 4;
        #pragma unroll
        for (int r = 0; r < 4; ++r) {
            out[(size_t)(row + r) * MM + mtile * 64 + w * 16 + li] = acc[rg][r];
        }
    }
}

// ---------------------------------------------------------------------------
extern "C" void kernel_launch(void* const* d_in, const int* in_sizes, int n_in,
                              void* d_out, int out_size, void* d_ws, size_t ws_size,
                              hipStream_t stream)
{
    const float* kvin = (const float*)d_in[0];
    const float* qin  = (const float*)d_in[1];
    const float* wq   = (const float*)d_in[2];
    const float* wk   = (const float*)d_in[3];
    const float* wv   = (const float*)d_in[4];
    const float* wo   = (const float*)d_in[5];
    float* out = (float*)d_out;

    char* ws = (char*)d_ws;
    const size_t SZ_X = (size_t)BB * CC * MM * 2;   // 8 MB
    const size_t SZ_W = (size_t)HH * MM * KK * 2;   // 2 MB
    short* xq  = (short*)(ws);
    short* xkv = (short*)(ws + SZ_X);
    short* wqt = (short*)(ws + 2 * SZ_X);
    short* wkt = (short*)(ws + 2 * SZ_X + SZ_W);
    short* wvt = (short*)(ws + 2 * SZ_X + 2 * SZ_W);
    short* wot = (short*)(ws + 2 * SZ_X + 3 * SZ_W);
    short* Qv  = (short*)(ws + 2 * SZ_X + 4 * SZ_W);
    short* Kv  = (short*)(ws + 3 * SZ_X + 4 * SZ_W);
    short* Vt  = (short*)(ws + 4 * SZ_X + 4 * SZ_W);
    short* pre = (short*)(ws + 5 * SZ_X + 4 * SZ_W);

    prep_kernel<<<1024, 256, 0, stream>>>(qin, kvin, wq, wk, wv, wo,
                                          xq, xkv, wqt, wkt, wvt, wot);
    proj_kernel<<<dim3(32, 32), 256, 0, stream>>>(xq, xkv, wqt, wkt, wvt, Qv, Kv, Vt);
    attn_kernel<<<dim3(16, 32), 256, 0, stream>>>(Qv, Kv, Vt, pre);
    outproj_kernel<<<dim3(16, 64), 256, 0, stream>>>(pre, wot, out);
}

// Round 3
// 282.636 us; speedup vs baseline: 2.1807x; 1.5752x over previous
//
#include <hip/hip_runtime.h>
#include <hip/hip_bf16.h>

#define BB 2
#define CC 2048
#define MM 1024
#define HH 16
#define KK 64

typedef __attribute__((ext_vector_type(8))) short bf16x8;
typedef __attribute__((ext_vector_type(4))) float f32x4;

__device__ __forceinline__ short f2bf(float f) {
    union { float f; unsigned int i; } u; u.f = f;
    unsigned int r = u.i + 0x7fffu + ((u.i >> 16) & 1u);
    return (short)(r >> 16);
}

__device__ __forceinline__ unsigned int cvtpk(float lo, float hi) {
    unsigned int d;
    asm("v_cvt_pk_bf16_f32 %0, %1, %2" : "=v"(d) : "v"(lo), "v"(hi));
    return d;
}

__device__ __forceinline__ float exp2v(float x) {
    float r;
    asm("v_exp_f32 %0, %1" : "=v"(r) : "v"(x));
    return r;
}

__device__ __forceinline__ f32x4 mfma16(bf16x8 a, bf16x8 b, f32x4 c) {
    return __builtin_amdgcn_mfma_f32_16x16x32_bf16(a, b, c, 0, 0, 0);
}

__device__ __forceinline__ void gload16(const void* g, void* l) {
    __builtin_amdgcn_global_load_lds(
        (const __attribute__((address_space(1))) unsigned int*)g,
        (__attribute__((address_space(3))) unsigned int*)l,
        16, 0, 0);
}

// ---------------------------------------------------------------------------
// prep: coalesced conversions + tile transposes (64x64 LDS tiles).
//   blocks 0..255   : wq/wk/wv  [h][m][k] -> [h][k][m] bf16
//   blocks 256..511 : wo        [hv][m]   -> [m][hv]   bf16
//   blocks 512..1023: qin/kvin  fp32 -> bf16 (straight copy)
// ---------------------------------------------------------------------------
__global__ __launch_bounds__(256) void prep_kernel(
    const float* __restrict__ qin, const float* __restrict__ kvin,
    const float* __restrict__ wq, const float* __restrict__ wk,
    const float* __restrict__ wv, const float* __restrict__ wo,
    short* __restrict__ xq, short* __restrict__ xkv,
    short* __restrict__ wqt, short* __restrict__ wkt,
    short* __restrict__ wvt, short* __restrict__ wot)
{
    __shared__ short tl[64][72];
    int b = blockIdx.x;
    int tid = threadIdx.x;

    if (b < 512) {
        int row = tid >> 2;
        int c0 = (tid & 3) * 16;
        int nw = (b < 256) ? 3 : 1;
        for (int w = 0; w < nw; ++w) {
            const float* src; short* dst; int srcStride, dstStride;
            if (b < 256) {
                int h = b >> 4, m0 = (b & 15) * 64;
                const float* wsrc = (w == 0) ? wq : (w == 1) ? wk : wv;
                short* wdst = (w == 0) ? wqt : (w == 1) ? wkt : wvt;
                src = wsrc + ((size_t)h * MM + m0) * KK;
                srcStride = KK;
                dst = wdst + (size_t)h * KK * MM + m0;
                dstStride = MM;
            } else {
                int b2 = b - 256;
                int hv0 = (b2 >> 4) * 64, m0 = (b2 & 15) * 64;
                src = wo + (size_t)hv0 * MM + m0;
                srcStride = MM;
                dst = wot + (size_t)m0 * (HH * KK) + hv0;
                dstStride = HH * KK;
            }
            float4 f0 = *(const float4*)(src + row * srcStride + c0);
            float4 f1 = *(const float4*)(src + row * srcStride + c0 + 4);
            float4 f2 = *(const float4*)(src + row * srcStride + c0 + 8);
            float4 f3 = *(const float4*)(src + row * srcStride + c0 + 12);
            tl[c0 + 0][row] = f2bf(f0.x);  tl[c0 + 1][row] = f2bf(f0.y);
            tl[c0 + 2][row] = f2bf(f0.z);  tl[c0 + 3][row] = f2bf(f0.w);
            tl[c0 + 4][row] = f2bf(f1.x);  tl[c0 + 5][row] = f2bf(f1.y);
            tl[c0 + 6][row] = f2bf(f1.z);  tl[c0 + 7][row] = f2bf(f1.w);
            tl[c0 + 8][row] = f2bf(f2.x);  tl[c0 + 9][row] = f2bf(f2.y);
            tl[c0 + 10][row] = f2bf(f2.z); tl[c0 + 11][row] = f2bf(f2.w);
            tl[c0 + 12][row] = f2bf(f3.x); tl[c0 + 13][row] = f2bf(f3.y);
            tl[c0 + 14][row] = f2bf(f3.z); tl[c0 + 15][row] = f2bf(f3.w);
            __syncthreads();
            int k = tid >> 2, s0 = (tid & 3) * 16;
            bf16x8 o0 = *(bf16x8*)&tl[k][s0];
            bf16x8 o1 = *(bf16x8*)&tl[k][s0 + 8];
            *(bf16x8*)(dst + (size_t)k * dstStride + s0) = o0;
            *(bf16x8*)(dst + (size_t)k * dstStride + s0 + 8) = o1;
            __syncthreads();
        }
    } else {
        int t = (b - 512) * 256 + tid;
        const float4* q4 = (const float4*)qin;
        const float4* k4 = (const float4*)kvin;
        #pragma unroll
        for (int i = 0; i < 8; ++i) {
            int idx = t + i * 131072;
            float4 a = q4[idx], c = k4[idx];
            short4 sa, sc;
            sa.x = f2bf(a.x); sa.y = f2bf(a.y); sa.z = f2bf(a.z); sa.w = f2bf(a.w);
            sc.x = f2bf(c.x); sc.y = f2bf(c.y); sc.z = f2bf(c.z); sc.w = f2bf(c.w);
            *(short4*)(xq + (size_t)idx * 4) = sa;
            *(short4*)(xkv + (size_t)idx * 4) = sc;
        }
    }
}

// ---------------------------------------------------------------------------
// gemm<MODE>: m97-structure GEMM, 128x128 tile, BK=64, 4 waves (64x64 each).
// global_load_lds(16B) staging with XOR-chunk swizzle applied BOTH sides:
//   store: LDS chunk (row, c') <- global chunk (row, c' ^ (row&7))
//   read : global chunk (row, c) is at LDS chunk (row, c ^ (row&7))
// => ds_read_b128 lands 2 lanes/bank (free); staging writes linear (required).
// MODE 0: proj.  A = xq (n<1024) else xkv; Bt = [wqt|wkt|wvt] [3072][1024].
//   outputs: Qv[bh][c][k] (*SCQ), Kv[bh][c][k], Vt[bh][v][c]. grid (24,32).
// MODE 1: outproj. A = pre [4096][1024]; Bt = wot [1024][1024]; fp32 out.
//   grid (8,32).
// ---------------------------------------------------------------------------
template<int MODE>
__global__ __launch_bounds__(256) void gemm_kernel(
    const short* __restrict__ Aq, const short* __restrict__ Akv,
    const short* __restrict__ Bt,
    short* __restrict__ Qv, short* __restrict__ Kv, short* __restrict__ Vt,
    float* __restrict__ outf)
{
    __shared__ short As[128 * 64];
    __shared__ short Bs[128 * 64];

    int tid = threadIdx.x;
    int wv = tid >> 6, ln = tid & 63;
    int g = ln >> 4, li = ln & 15;
    int wr = wv >> 1, wc = wv & 1;

    int ncol0 = blockIdx.x * 128;
    int row0  = blockIdx.y * 128;

    const short* Abase = (MODE == 0) ? (ncol0 < 1024 ? Aq : Akv) : Aq;

    // staging addresses: chunk s = (wv*4+i)*64 + ln
    const char* aSrc[4]; const char* bSrc[4];
    short* aDst[4]; short* bDst[4];
    #pragma unroll
    for (int i = 0; i < 4; ++i) {
        int s = (wv * 4 + i) * 64 + ln;
        int row = s >> 3, cp = s & 7;
        int c = cp ^ (row & 7);
        aSrc[i] = (const char*)(Abase + (size_t)(row0 + row) * MM) + c * 16;
        bSrc[i] = (const char*)(Bt + (size_t)(ncol0 + row) * MM) + c * 16;
        aDst[i] = As + (wv * 4 + i) * 512;
        bDst[i] = Bs + (wv * 4 + i) * 512;
    }

    // LDS read addresses (shorts): row*64 + swizzled_chunk*8
    int sA = li & 7;
    const short* aRd[4][2]; const short* bRd[4][2];
    #pragma unroll
    for (int i = 0; i < 4; ++i) {
        int ra = wr * 64 + i * 16 + li;
        aRd[i][0] = As + ra * 64 + (g ^ sA) * 8;
        aRd[i][1] = As + ra * 64 + ((g + 4) ^ sA) * 8;
        int rb = wc * 64 + i * 16 + li;
        bRd[i][0] = Bs + rb * 64 + (g ^ sA) * 8;
        bRd[i][1] = Bs + rb * 64 + ((g + 4) ^ sA) * 8;
    }

    f32x4 acc[4][4];
    #pragma unroll
    for (int mi = 0; mi < 4; ++mi)
        #pragma unroll
        for (int ni = 0; ni < 4; ++ni)
            acc[mi][ni] = (f32x4){0.f, 0.f, 0.f, 0.f};

    for (int kt = 0; kt < 16; ++kt) {
        size_t ko = (size_t)kt * 128;   // 64 bf16 = 128 B per K-step
        #pragma unroll
        for (int i = 0; i < 4; ++i) {
            gload16(aSrc[i] + ko, aDst[i]);
            gload16(bSrc[i] + ko, bDst[i]);
        }
        __syncthreads();   // drains vmcnt before barrier (compiler-enforced)

        bf16x8 af[4][2], bfr[4][2];
        #pragma unroll
        for (int mi = 0; mi < 4; ++mi) {
            af[mi][0] = *(const bf16x8*)aRd[mi][0];
            af[mi][1] = *(const bf16x8*)aRd[mi][1];
        }
        #pragma unroll
        for (int ni = 0; ni < 4; ++ni) {
            bfr[ni][0] = *(const bf16x8*)bRd[ni][0];
            bfr[ni][1] = *(const bf16x8*)bRd[ni][1];
        }
        #pragma unroll
        for (int mi = 0; mi < 4; ++mi)
            #pragma unroll
            for (int ni = 0; ni < 4; ++ni) {
                acc[mi][ni] = mfma16(af[mi][0], bfr[ni][0], acc[mi][ni]);
                acc[mi][ni] = mfma16(af[mi][1], bfr[ni][1], acc[mi][ni]);
            }
        __syncthreads();
    }

    if (MODE == 0) {
        const float SCQ = 0.125f * 1.44269504f;
        int region = ncol0 >> 10;              // 0=Q, 1=K, 2=V
        int nloc0 = (ncol0 & 1023) + wc * 64;
        #pragma unroll
        for (int mi = 0; mi < 4; ++mi) {
            int grow0 = row0 + wr * 64 + mi * 16 + g * 4;
            int b = grow0 >> 11;
            int c0 = grow0 & 2047;
            #pragma unroll
            for (int ni = 0; ni < 4; ++ni) {
                int nloc = nloc0 + ni * 16 + li;
                int h = nloc >> 6, kv = nloc & 63;
                size_t bh = (size_t)b * 16 + h;
                if (region == 0) {
                    short* p = Qv + (bh * CC + c0) * KK + kv;
                    p[0]      = f2bf(acc[mi][ni][0] * SCQ);
                    p[KK]     = f2bf(acc[mi][ni][1] * SCQ);
                    p[2 * KK] = f2bf(acc[mi][ni][2] * SCQ);
                    p[3 * KK] = f2bf(acc[mi][ni][3] * SCQ);
                } else if (region == 1) {
                    short* p = Kv + (bh * CC + c0) * KK + kv;
                    p[0]      = f2bf(acc[mi][ni][0]);
                    p[KK]     = f2bf(acc[mi][ni][1]);
                    p[2 * KK] = f2bf(acc[mi][ni][2]);
                    p[3 * KK] = f2bf(acc[mi][ni][3]);
                } else {
                    uint2 u;
                    u.x = cvtpk(acc[mi][ni][0], acc[mi][ni][1]);
                    u.y = cvtpk(acc[mi][ni][2], acc[mi][ni][3]);
                    *(uint2*)(Vt + (bh * KK + kv) * CC + c0) = u;
                }
            }
        }
    } else {
        #pragma unroll
        for (int mi = 0; mi < 4; ++mi) {
            int grow0 = row0 + wr * 64 + mi * 16 + g * 4;
            #pragma unroll
            for (int ni = 0; ni < 4; ++ni) {
                int n = ncol0 + wc * 64 + ni * 16 + li;
                #pragma unroll
                for (int r = 0; r < 4; ++r)
                    outf[(size_t)(grow0 + r) * MM + n] = acc[mi][ni][r];
            }
        }
    }
}

// ---------------------------------------------------------------------------
// attn: non-online softmax, swapped QK^T (unchanged from round 2).
// ---------------------------------------------------------------------------
__global__ __launch_bounds__(256) void attn_kernel(
    const short* __restrict__ Qv, const short* __restrict__ Kv,
    const short* __restrict__ Vt, short* __restrict__ pre)
{
    int dtile = blockIdx.x;
    int bh = blockIdx.y;
    int b = bh >> 4, h = bh & 15;
    int wave = threadIdx.x >> 6, lane = threadIdx.x & 63;
    int g = lane >> 4, li = lane & 15;
    int d0 = dtile * 128 + wave * 32;

    __shared__ unsigned int plds[4 * 1024];

    int sw = ((li & 3) << 3) | (((li >> 2) & 1) << 2);
    unsigned int* wbase = plds + wave * 1024 + li * 32;
    unsigned int* wa0 = wbase + (((0 << 3) | (g << 1)) ^ sw);
    unsigned int* wa1 = wbase + (((1 << 3) | (g << 1)) ^ sw);
    unsigned int* wa2 = wbase + (((2 << 3) | (g << 1)) ^ sw);
    unsigned int* wa3 = wbase + (((3 << 3) | (g << 1)) ^ sw);
    unsigned int* ra0 = wbase + (((0 << 4) | (g << 2)) ^ sw);
    unsigned int* ra1 = wbase + (((1 << 4) | (g << 2)) ^ sw);

    const short* qb = Qv + ((size_t)bh * CC + d0 + li) * KK + g * 8;
    bf16x8 qA0 = *(const bf16x8*)qb;
    bf16x8 qA1 = *(const bf16x8*)(qb + 32);
    bf16x8 qB0 = *(const bf16x8*)(qb + 16 * KK);
    bf16x8 qB1 = *(const bf16x8*)(qb + 16 * KK + 32);

    f32x4 oA[4], oB[4];
    #pragma unroll
    for (int i = 0; i < 4; ++i) {
        oA[i] = (f32x4){0.f, 0.f, 0.f, 0.f};
        oB[i] = (f32x4){0.f, 0.f, 0.f, 0.f};
    }
    float lsA = 0.f, lsB = 0.f;

    const short* kT = Kv + (size_t)bh * CC * KK + li * KK + g * 8;
    const short* vT = Vt + (size_t)bh * KK * CC + li * CC + g * 8;

    for (int ct = 0; ct < CC; ct += 64) {
        f32x4 sA[4], sB[4];
        #pragma unroll
        for (int cb = 0; cb < 4; ++cb) {
            const short* kp = kT + (size_t)cb * 16 * KK;
            bf16x8 k0 = *(const bf16x8*)kp;
            bf16x8 k1 = *(const bf16x8*)(kp + 32);
            f32x4 z = (f32x4){0.f, 0.f, 0.f, 0.f};
            z = mfma16(k0, qA0, z);
            sA[cb] = mfma16(k1, qA1, z);
            f32x4 z2 = (f32x4){0.f, 0.f, 0.f, 0.f};
            z2 = mfma16(k0, qB0, z2);
            sB[cb] = mfma16(k1, qB1, z2);
        }
        kT += 64 * KK;
        {
            float p[16];
            #pragma unroll
            for (int cb = 0; cb < 4; ++cb)
                #pragma unroll
                for (int r = 0; r < 4; ++r) p[cb * 4 + r] = exp2v(sA[cb][r]);
            float t0 = (p[0] + p[1]) + (p[2] + p[3]);
            float t1 = (p[4] + p[5]) + (p[6] + p[7]);
            float t2 = (p[8] + p[9]) + (p[10] + p[11]);
            float t3 = (p[12] + p[13]) + (p[14] + p[15]);
            lsA += (t0 + t1) + (t2 + t3);
            uint2 v;
            v.x = cvtpk(p[0], p[1]);  v.y = cvtpk(p[2], p[3]);   *(uint2*)wa0 = v;
            v.x = cvtpk(p[4], p[5]);  v.y = cvtpk(p[6], p[7]);   *(uint2*)wa1 = v;
            v.x = cvtpk(p[8], p[9]);  v.y = cvtpk(p[10], p[11]); *(uint2*)wa2 = v;
            v.x = cvtpk(p[12], p[13]); v.y = cvtpk(p[14], p[15]); *(uint2*)wa3 = v;
        }
        {
            float p[16];
            #pragma unroll
            for (int cb = 0; cb < 4; ++cb)
                #pragma unroll
                for (int r = 0; r < 4; ++r) p[cb * 4 + r] = exp2v(sB[cb][r]);
            float t0 = (p[0] + p[1]) + (p[2] + p[3]);
            float t1 = (p[4] + p[5]) + (p[6] + p[7]);
            float t2 = (p[8] + p[9]) + (p[10] + p[11]);
            float t3 = (p[12] + p[13]) + (p[14] + p[15]);
            lsB += (t0 + t1) + (t2 + t3);
            uint2 v;
            v.x = cvtpk(p[0], p[1]);  v.y = cvtpk(p[2], p[3]);   *(uint2*)(wa0 + 512) = v;
            v.x = cvtpk(p[4], p[5]);  v.y = cvtpk(p[6], p[7]);   *(uint2*)(wa1 + 512) = v;
            v.x = cvtpk(p[8], p[9]);  v.y = cvtpk(p[10], p[11]); *(uint2*)(wa2 + 512) = v;
            v.x = cvtpk(p[12], p[13]); v.y = cvtpk(p[14], p[15]); *(uint2*)(wa3 + 512) = v;
        }
        bf16x8 pA0 = *(bf16x8*)ra0;
        bf16x8 pA1 = *(bf16x8*)ra1;
        bf16x8 pB0 = *(bf16x8*)(ra0 + 512);
        bf16x8 pB1 = *(bf16x8*)(ra1 + 512);
        #pragma unroll
        for (int cbv = 0; cbv < 4; ++cbv) {
            const short* vp = vT + (size_t)cbv * 16 * CC + ct;
            bf16x8 v0 = *(const bf16x8*)vp;
            bf16x8 v1 = *(const bf16x8*)(vp + 32);
            oA[cbv] = mfma16(v0, pA0, oA[cbv]);
            oA[cbv] = mfma16(v1, pA1, oA[cbv]);
            oB[cbv] = mfma16(v0, pB0, oB[cbv]);
            oB[cbv] = mfma16(v1, pB1, oB[cbv]);
        }
    }

    lsA += __shfl_xor(lsA, 16); lsA += __shfl_xor(lsA, 32);
    lsB += __shfl_xor(lsB, 16); lsB += __shfl_xor(lsB, 32);
    float rA = 1.0f / lsA, rB = 1.0f / lsB;

    short* prA = pre + ((size_t)b * CC + d0 + li) * (HH * KK) + h * KK + g * 4;
    short* prB = prA + (size_t)16 * (HH * KK);
    #pragma unroll
    for (int cbv = 0; cbv < 4; ++cbv) {
        uint2 u;
        u.x = cvtpk(oA[cbv][0] * rA, oA[cbv][1] * rA);
        u.y = cvtpk(oA[cbv][2] * rA, oA[cbv][3] * rA);
        *(uint2*)(prA + cbv * 16) = u;
        u.x = cvtpk(oB[cbv][0] * rB, oB[cbv][1] * rB);
        u.y = cvtpk(oB[cbv][2] * rB, oB[cbv][3] * rB);
        *(uint2*)(prB + cbv * 16) = u;
    }
}

// ---------------------------------------------------------------------------
extern "C" void kernel_launch(void* const* d_in, const int* in_sizes, int n_in,
                              void* d_out, int out_size, void* d_ws, size_t ws_size,
                              hipStream_t stream)
{
    const float* kvin = (const float*)d_in[0];
    const float* qin  = (const float*)d_in[1];
    const float* wq   = (const float*)d_in[2];
    const float* wk   = (const float*)d_in[3];
    const float* wv   = (const float*)d_in[4];
    const float* wo   = (const float*)d_in[5];
    float* out = (float*)d_out;

    char* ws = (char*)d_ws;
    const size_t SZ_X = (size_t)BB * CC * MM * 2;   // 8 MB
    const size_t SZ_W = (size_t)HH * MM * KK * 2;   // 2 MB
    short* xq  = (short*)(ws);
    short* xkv = (short*)(ws + SZ_X);
    short* wqt = (short*)(ws + 2 * SZ_X);
    short* wkt = (short*)(ws + 2 * SZ_X + SZ_W);
    short* wvt = (short*)(ws + 2 * SZ_X + 2 * SZ_W);
    short* wot = (short*)(ws + 2 * SZ_X + 3 * SZ_W);
    short* Qv  = (short*)(ws + 2 * SZ_X + 4 * SZ_W);
    short* Kv  = (short*)(ws + 3 * SZ_X + 4 * SZ_W);
    short* Vt  = (short*)(ws + 4 * SZ_X + 4 * SZ_W);
    short* pre = (short*)(ws + 5 * SZ_X + 4 * SZ_W);

    prep_kernel<<<1024, 256, 0, stream>>>(qin, kvin, wq, wk, wv, wo,
                                          xq, xkv, wqt, wkt, wvt, wot);
    gemm_kernel<0><<<dim3(24, 32), 256, 0, stream>>>(xq, xkv, wqt,
                                                     Qv, Kv, Vt, nullptr);
    attn_kernel<<<dim3(16, 32), 256, 0, stream>>>(Qv, Kv, Vt, pre);
    gemm_kernel<1><<<dim3(8, 32), 256, 0, stream>>>(pre, nullptr, wot,
                                                    nullptr, nullptr, nullptr, out);
}

// Round 11
// 277.569 us; speedup vs baseline: 2.2205x; 1.0183x over previous
//
#include <hip/hip_runtime.h>
#include <hip/hip_bf16.h>

#define BB 2
#define CC 2048
#define MM 1024
#define HH 16
#define KK 64

typedef __attribute__((ext_vector_type(8))) short bf16x8;
typedef __attribute__((ext_vector_type(4))) float f32x4;

__device__ __forceinline__ short f2bf(float f) {
    union { float f; unsigned int i; } u; u.f = f;
    unsigned int r = u.i + 0x7fffu + ((u.i >> 16) & 1u);
    return (short)(r >> 16);
}

__device__ __forceinline__ unsigned int cvtpk(float lo, float hi) {
    unsigned int d;
    asm("v_cvt_pk_bf16_f32 %0, %1, %2" : "=v"(d) : "v"(lo), "v"(hi));
    return d;
}

__device__ __forceinline__ float exp2v(float x) {
    float r;
    asm("v_exp_f32 %0, %1" : "=v"(r) : "v"(x));
    return r;
}

__device__ __forceinline__ f32x4 mfma16(bf16x8 a, bf16x8 b, f32x4 c) {
    return __builtin_amdgcn_mfma_f32_16x16x32_bf16(a, b, c, 0, 0, 0);
}

__device__ __forceinline__ void gload16(const void* g, void* l) {
    __builtin_amdgcn_global_load_lds(
        (const __attribute__((address_space(1))) unsigned int*)g,
        (__attribute__((address_space(3))) unsigned int*)l,
        16, 0, 0);
}

// ---------------------------------------------------------------------------
// prep: coalesced conversions + tile transposes (64x64 LDS tiles). (validated)
// ---------------------------------------------------------------------------
__global__ __launch_bounds__(256) void prep_kernel(
    const float* __restrict__ qin, const float* __restrict__ kvin,
    const float* __restrict__ wq, const float* __restrict__ wk,
    const float* __restrict__ wv, const float* __restrict__ wo,
    short* __restrict__ xq, short* __restrict__ xkv,
    short* __restrict__ wqt, short* __restrict__ wkt,
    short* __restrict__ wvt, short* __restrict__ wot)
{
    __shared__ short tl[64][72];
    int b = blockIdx.x;
    int tid = threadIdx.x;

    if (b < 512) {
        int row = tid >> 2;
        int c0 = (tid & 3) * 16;
        int nw = (b < 256) ? 3 : 1;
        for (int w = 0; w < nw; ++w) {
            const float* src; short* dst; int srcStride, dstStride;
            if (b < 256) {
                int h = b >> 4, m0 = (b & 15) * 64;
                const float* wsrc = (w == 0) ? wq : (w == 1) ? wk : wv;
                short* wdst = (w == 0) ? wqt : (w == 1) ? wkt : wvt;
                src = wsrc + ((size_t)h * MM + m0) * KK;
                srcStride = KK;
                dst = wdst + (size_t)h * KK * MM + m0;
                dstStride = MM;
            } else {
                int b2 = b - 256;
                int hv0 = (b2 >> 4) * 64, m0 = (b2 & 15) * 64;
                src = wo + (size_t)hv0 * MM + m0;
                srcStride = MM;
                dst = wot + (size_t)m0 * (HH * KK) + hv0;
                dstStride = HH * KK;
            }
            float4 f0 = *(const float4*)(src + row * srcStride + c0);
            float4 f1 = *(const float4*)(src + row * srcStride + c0 + 4);
            float4 f2 = *(const float4*)(src + row * srcStride + c0 + 8);
            float4 f3 = *(const float4*)(src + row * srcStride + c0 + 12);
            tl[c0 + 0][row] = f2bf(f0.x);  tl[c0 + 1][row] = f2bf(f0.y);
            tl[c0 + 2][row] = f2bf(f0.z);  tl[c0 + 3][row] = f2bf(f0.w);
            tl[c0 + 4][row] = f2bf(f1.x);  tl[c0 + 5][row] = f2bf(f1.y);
            tl[c0 + 6][row] = f2bf(f1.z);  tl[c0 + 7][row] = f2bf(f1.w);
            tl[c0 + 8][row] = f2bf(f2.x);  tl[c0 + 9][row] = f2bf(f2.y);
            tl[c0 + 10][row] = f2bf(f2.z); tl[c0 + 11][row] = f2bf(f2.w);
            tl[c0 + 12][row] = f2bf(f3.x); tl[c0 + 13][row] = f2bf(f3.y);
            tl[c0 + 14][row] = f2bf(f3.z); tl[c0 + 15][row] = f2bf(f3.w);
            __syncthreads();
            int k = tid >> 2, s0 = (tid & 3) * 16;
            bf16x8 o0 = *(bf16x8*)&tl[k][s0];
            bf16x8 o1 = *(bf16x8*)&tl[k][s0 + 8];
            *(bf16x8*)(dst + (size_t)k * dstStride + s0) = o0;
            *(bf16x8*)(dst + (size_t)k * dstStride + s0 + 8) = o1;
            __syncthreads();
        }
    } else {
        int t = (b - 512) * 256 + tid;
        const float4* q4 = (const float4*)qin;
        const float4* k4 = (const float4*)kvin;
        #pragma unroll
        for (int i = 0; i < 8; ++i) {
            int idx = t + i * 131072;
            float4 a = q4[idx], c = k4[idx];
            short4 sa, sc;
            sa.x = f2bf(a.x); sa.y = f2bf(a.y); sa.z = f2bf(a.z); sa.w = f2bf(a.w);
            sc.x = f2bf(c.x); sc.y = f2bf(c.y); sc.z = f2bf(c.z); sc.w = f2bf(c.w);
            *(short4*)(xq + (size_t)idx * 4) = sa;
            *(short4*)(xkv + (size_t)idx * 4) = sc;
        }
    }
}

// ---------------------------------------------------------------------------
// gemm<MODE>: m97-structure GEMM, 128x128 tile, BK=64 (validated).
// ---------------------------------------------------------------------------
template<int MODE>
__global__ __launch_bounds__(256) void gemm_kernel(
    const short* __restrict__ Aq, const short* __restrict__ Akv,
    const short* __restrict__ Bt,
    short* __restrict__ Qv, short* __restrict__ Kv, short* __restrict__ Vt,
    float* __restrict__ outf)
{
    __shared__ short As[128 * 64];
    __shared__ short Bs[128 * 64];

    int tid = threadIdx.x;
    int wv = tid >> 6, ln = tid & 63;
    int g = ln >> 4, li = ln & 15;
    int wr = wv >> 1, wc = wv & 1;

    int ncol0 = blockIdx.x * 128;
    int row0  = blockIdx.y * 128;

    const short* Abase = (MODE == 0) ? (ncol0 < 1024 ? Aq : Akv) : Aq;

    const char* aSrc[4]; const char* bSrc[4];
    short* aDst[4]; short* bDst[4];
    #pragma unroll
    for (int i = 0; i < 4; ++i) {
        int s = (wv * 4 + i) * 64 + ln;
        int row = s >> 3, cp = s & 7;
        int c = cp ^ (row & 7);
        aSrc[i] = (const char*)(Abase + (size_t)(row0 + row) * MM) + c * 16;
        bSrc[i] = (const char*)(Bt + (size_t)(ncol0 + row) * MM) + c * 16;
        aDst[i] = As + (wv * 4 + i) * 512;
        bDst[i] = Bs + (wv * 4 + i) * 512;
    }

    int sA = li & 7;
    const short* aRd[4][2]; const short* bRd[4][2];
    #pragma unroll
    for (int i = 0; i < 4; ++i) {
        int ra = wr * 64 + i * 16 + li;
        aRd[i][0] = As + ra * 64 + (g ^ sA) * 8;
        aRd[i][1] = As + ra * 64 + ((g + 4) ^ sA) * 8;
        int rb = wc * 64 + i * 16 + li;
        bRd[i][0] = Bs + rb * 64 + (g ^ sA) * 8;
        bRd[i][1] = Bs + rb * 64 + ((g + 4) ^ sA) * 8;
    }

    f32x4 acc[4][4];
    #pragma unroll
    for (int mi = 0; mi < 4; ++mi)
        #pragma unroll
        for (int ni = 0; ni < 4; ++ni)
            acc[mi][ni] = (f32x4){0.f, 0.f, 0.f, 0.f};

    for (int kt = 0; kt < 16; ++kt) {
        size_t ko = (size_t)kt * 128;
        #pragma unroll
        for (int i = 0; i < 4; ++i) {
            gload16(aSrc[i] + ko, aDst[i]);
            gload16(bSrc[i] + ko, bDst[i]);
        }
        __syncthreads();

        bf16x8 af[4][2], bfr[4][2];
        #pragma unroll
        for (int mi = 0; mi < 4; ++mi) {
            af[mi][0] = *(const bf16x8*)aRd[mi][0];
            af[mi][1] = *(const bf16x8*)aRd[mi][1];
        }
        #pragma unroll
        for (int ni = 0; ni < 4; ++ni) {
            bfr[ni][0] = *(const bf16x8*)bRd[ni][0];
            bfr[ni][1] = *(const bf16x8*)bRd[ni][1];
        }
        #pragma unroll
        for (int mi = 0; mi < 4; ++mi)
            #pragma unroll
            for (int ni = 0; ni < 4; ++ni) {
                acc[mi][ni] = mfma16(af[mi][0], bfr[ni][0], acc[mi][ni]);
                acc[mi][ni] = mfma16(af[mi][1], bfr[ni][1], acc[mi][ni]);
            }
        __syncthreads();
    }

    if (MODE == 0) {
        const float SCQ = 0.125f * 1.44269504f;
        int region = ncol0 >> 10;
        int nloc0 = (ncol0 & 1023) + wc * 64;
        #pragma unroll
        for (int mi = 0; mi < 4; ++mi) {
            int grow0 = row0 + wr * 64 + mi * 16 + g * 4;
            int b = grow0 >> 11;
            int c0 = grow0 & 2047;
            #pragma unroll
            for (int ni = 0; ni < 4; ++ni) {
                int nloc = nloc0 + ni * 16 + li;
                int h = nloc >> 6, kv = nloc & 63;
                size_t bh = (size_t)b * 16 + h;
                if (region == 0) {
                    short* p = Qv + (bh * CC + c0) * KK + kv;
                    p[0]      = f2bf(acc[mi][ni][0] * SCQ);
                    p[KK]     = f2bf(acc[mi][ni][1] * SCQ);
                    p[2 * KK] = f2bf(acc[mi][ni][2] * SCQ);
                    p[3 * KK] = f2bf(acc[mi][ni][3] * SCQ);
                } else if (region == 1) {
                    short* p = Kv + (bh * CC + c0) * KK + kv;
                    p[0]      = f2bf(acc[mi][ni][0]);
                    p[KK]     = f2bf(acc[mi][ni][1]);
                    p[2 * KK] = f2bf(acc[mi][ni][2]);
                    p[3 * KK] = f2bf(acc[mi][ni][3]);
                } else {
                    uint2 u;
                    u.x = cvtpk(acc[mi][ni][0], acc[mi][ni][1]);
                    u.y = cvtpk(acc[mi][ni][2], acc[mi][ni][3]);
                    *(uint2*)(Vt + (bh * KK + kv) * CC + c0) = u;
                }
            }
        }
    } else {
        #pragma unroll
        for (int mi = 0; mi < 4; ++mi) {
            int grow0 = row0 + wr * 64 + mi * 16 + g * 4;
            #pragma unroll
            for (int ni = 0; ni < 4; ++ni) {
                int n = ncol0 + wc * 64 + ni * 16 + li;
                #pragma unroll
                for (int r = 0; r < 4; ++r)
                    outf[(size_t)(grow0 + r) * MM + n] = acc[mi][ni][r];
            }
        }
    }
}

// ---------------------------------------------------------------------------
// attn: EXACT R2-validated body (swapped QK^T, non-online softmax, XOR-swizzle
// P staging, launch_bounds(256) -- NO min-waves clause; (256,2) correlates
// with 4/4 correctness failures) with ONE delta:
//   V-fragment loads hoisted to the top of the loop body so their ~200-cyc
//   L2 latency hides under the 8 QK^T MFMAs + softmax VALU.
// grid (16, 32).
// ---------------------------------------------------------------------------
__global__ __launch_bounds__(256) void attn_kernel(
    const short* __restrict__ Qv, const short* __restrict__ Kv,
    const short* __restrict__ Vt, short* __restrict__ pre)
{
    int dtile = blockIdx.x;
    int bh = blockIdx.y;
    int b = bh >> 4, h = bh & 15;
    int wave = threadIdx.x >> 6, lane = threadIdx.x & 63;
    int g = lane >> 4, li = lane & 15;
    int d0 = dtile * 128 + wave * 32;

    __shared__ unsigned int plds[4 * 1024];

    int sw = ((li & 3) << 3) | (((li >> 2) & 1) << 2);
    unsigned int* wbase = plds + wave * 1024 + li * 32;
    unsigned int* wa0 = wbase + (((0 << 3) | (g << 1)) ^ sw);
    unsigned int* wa1 = wbase + (((1 << 3) | (g << 1)) ^ sw);
    unsigned int* wa2 = wbase + (((2 << 3) | (g << 1)) ^ sw);
    unsigned int* wa3 = wbase + (((3 << 3) | (g << 1)) ^ sw);
    unsigned int* ra0 = wbase + (((0 << 4) | (g << 2)) ^ sw);
    unsigned int* ra1 = wbase + (((1 << 4) | (g << 2)) ^ sw);

    const short* qb = Qv + ((size_t)bh * CC + d0 + li) * KK + g * 8;
    bf16x8 qA0 = *(const bf16x8*)qb;
    bf16x8 qA1 = *(const bf16x8*)(qb + 32);
    bf16x8 qB0 = *(const bf16x8*)(qb + 16 * KK);
    bf16x8 qB1 = *(const bf16x8*)(qb + 16 * KK + 32);

    f32x4 oA[4], oB[4];
    #pragma unroll
    for (int i = 0; i < 4; ++i) {
        oA[i] = (f32x4){0.f, 0.f, 0.f, 0.f};
        oB[i] = (f32x4){0.f, 0.f, 0.f, 0.f};
    }
    float lsA = 0.f, lsB = 0.f;

    const short* kT = Kv + (size_t)bh * CC * KK + li * KK + g * 8;
    const short* vT = Vt + (size_t)bh * KK * CC + li * CC + g * 8;

    for (int ct = 0; ct < CC; ct += 64) {
        // ---- V fragments issued first: latency hides under S^T + softmax ----
        bf16x8 vf[4][2];
        #pragma unroll
        for (int cbv = 0; cbv < 4; ++cbv) {
            const short* vp = vT + (size_t)cbv * 16 * CC + ct;
            vf[cbv][0] = *(const bf16x8*)vp;
            vf[cbv][1] = *(const bf16x8*)(vp + 32);
        }
        // ---- S^T for both halves ----
        f32x4 sA[4], sB[4];
        #pragma unroll
        for (int cb = 0; cb < 4; ++cb) {
            const short* kp = kT + (size_t)cb * 16 * KK;
            bf16x8 k0 = *(const bf16x8*)kp;
            bf16x8 k1 = *(const bf16x8*)(kp + 32);
            f32x4 z = (f32x4){0.f, 0.f, 0.f, 0.f};
            z = mfma16(k0, qA0, z);
            sA[cb] = mfma16(k1, qA1, z);
            f32x4 z2 = (f32x4){0.f, 0.f, 0.f, 0.f};
            z2 = mfma16(k0, qB0, z2);
            sB[cb] = mfma16(k1, qB1, z2);
        }
        kT += 64 * KK;
        // ---- exp2 + partial sums + pack + LDS (half A then half B) ----
        {
            float p[16];
            #pragma unroll
            for (int cb = 0; cb < 4; ++cb)
                #pragma unroll
                for (int r = 0; r < 4; ++r) p[cb * 4 + r] = exp2v(sA[cb][r]);
            float t0 = (p[0] + p[1]) + (p[2] + p[3]);
            float t1 = (p[4] + p[5]) + (p[6] + p[7]);
            float t2 = (p[8] + p[9]) + (p[10] + p[11]);
            float t3 = (p[12] + p[13]) + (p[14] + p[15]);
            lsA += (t0 + t1) + (t2 + t3);
            uint2 v;
            v.x = cvtpk(p[0], p[1]);  v.y = cvtpk(p[2], p[3]);   *(uint2*)wa0 = v;
            v.x = cvtpk(p[4], p[5]);  v.y = cvtpk(p[6], p[7]);   *(uint2*)wa1 = v;
            v.x = cvtpk(p[8], p[9]);  v.y = cvtpk(p[10], p[11]); *(uint2*)wa2 = v;
            v.x = cvtpk(p[12], p[13]); v.y = cvtpk(p[14], p[15]); *(uint2*)wa3 = v;
        }
        {
            float p[16];
            #pragma unroll
            for (int cb = 0; cb < 4; ++cb)
                #pragma unroll
                for (int r = 0; r < 4; ++r) p[cb * 4 + r] = exp2v(sB[cb][r]);
            float t0 = (p[0] + p[1]) + (p[2] + p[3]);
            float t1 = (p[4] + p[5]) + (p[6] + p[7]);
            float t2 = (p[8] + p[9]) + (p[10] + p[11]);
            float t3 = (p[12] + p[13]) + (p[14] + p[15]);
            lsB += (t0 + t1) + (t2 + t3);
            uint2 v;
            v.x = cvtpk(p[0], p[1]);  v.y = cvtpk(p[2], p[3]);   *(uint2*)(wa0 + 512) = v;
            v.x = cvtpk(p[4], p[5]);  v.y = cvtpk(p[6], p[7]);   *(uint2*)(wa1 + 512) = v;
            v.x = cvtpk(p[8], p[9]);  v.y = cvtpk(p[10], p[11]); *(uint2*)(wa2 + 512) = v;
            v.x = cvtpk(p[12], p[13]); v.y = cvtpk(p[14], p[15]); *(uint2*)(wa3 + 512) = v;
        }
        // ---- read P^T fragments (B operand) ----
        bf16x8 pA0 = *(bf16x8*)ra0;
        bf16x8 pA1 = *(bf16x8*)ra1;
        bf16x8 pB0 = *(bf16x8*)(ra0 + 512);
        bf16x8 pB1 = *(bf16x8*)(ra1 + 512);
        // ---- O^T += V^T P^T ----
        #pragma unroll
        for (int cbv = 0; cbv < 4; ++cbv) {
            oA[cbv] = mfma16(vf[cbv][0], pA0, oA[cbv]);
            oA[cbv] = mfma16(vf[cbv][1], pA1, oA[cbv]);
            oB[cbv] = mfma16(vf[cbv][0], pB0, oB[cbv]);
            oB[cbv] = mfma16(vf[cbv][1], pB1, oB[cbv]);
        }
    }

    lsA += __shfl_xor(lsA, 16); lsA += __shfl_xor(lsA, 32);
    lsB += __shfl_xor(lsB, 16); lsB += __shfl_xor(lsB, 32);
    float rA = 1.0f / lsA, rB = 1.0f / lsB;

    short* prA = pre + ((size_t)b * CC + d0 + li) * (HH * KK) + h * KK + g * 4;
    short* prB = prA + (size_t)16 * (HH * KK);
    #pragma unroll
    for (int cbv = 0; cbv < 4; ++cbv) {
        uint2 u;
        u.x = cvtpk(oA[cbv][0] * rA, oA[cbv][1] * rA);
        u.y = cvtpk(oA[cbv][2] * rA, oA[cbv][3] * rA);
        *(uint2*)(prA + cbv * 16) = u;
        u.x = cvtpk(oB[cbv][0] * rB, oB[cbv][1] * rB);
        u.y = cvtpk(oB[cbv][2] * rB, oB[cbv][3] * rB);
        *(uint2*)(prB + cbv * 16) = u;
    }
}

// ---------------------------------------------------------------------------
extern "C" void kernel_launch(void* const* d_in, const int* in_sizes, int n_in,
                              void* d_out, int out_size, void* d_ws, size_t ws_size,
                              hipStream_t stream)
{
    const float* kvin = (const float*)d_in[0];
    const float* qin  = (const float*)d_in[1];
    const float* wq   = (const float*)d_in[2];
    const float* wk   = (const float*)d_in[3];
    const float* wv   = (const float*)d_in[4];
    const float* wo   = (const float*)d_in[5];
    float* out = (float*)d_out;

    char* ws = (char*)d_ws;
    const size_t SZ_X = (size_t)BB * CC * MM * 2;   // 8 MB
    const size_t SZ_W = (size_t)HH * MM * KK * 2;   // 2 MB
    short* xq  = (short*)(ws);
    short* xkv = (short*)(ws + SZ_X);
    short* wqt = (short*)(ws + 2 * SZ_X);
    short* wkt = (short*)(ws + 2 * SZ_X + SZ_W);
    short* wvt = (short*)(ws + 2 * SZ_X + 2 * SZ_W);
    short* wot = (short*)(ws + 2 * SZ_X + 3 * SZ_W);
    short* Qv  = (short*)(ws + 2 * SZ_X + 4 * SZ_W);
    short* Kv  = (short*)(ws + 3 * SZ_X + 4 * SZ_W);
    short* Vt  = (short*)(ws + 4 * SZ_X + 4 * SZ_W);
    short* pre = (short*)(ws + 5 * SZ_X + 4 * SZ_W);

    prep_kernel<<<1024, 256, 0, stream>>>(qin, kvin, wq, wk, wv, wo,
                                          xq, xkv, wqt, wkt, wvt, wot);
    gemm_kernel<0><<<dim3(24, 32), 256, 0, stream>>>(xq, xkv, wqt,
                                                     Qv, Kv, Vt, nullptr);
    attn_kernel<<<dim3(16, 32), 256, 0, stream>>>(Qv, Kv, Vt, pre);
    gemm_kernel<1><<<dim3(8, 32), 256, 0, stream>>>(pre, nullptr, wot,
                                                    nullptr, nullptr, nullptr, out);
}